// Round 2
// baseline (289.032 us; speedup 1.0000x reference)
//
#include <hip/hip_runtime.h>

typedef _Float16 half8 __attribute__((ext_vector_type(8)));
typedef float floatx4 __attribute__((ext_vector_type(4)));

#define INV_TEMP 0.08838834764831845f

// workspace layout (bytes)
#define OFF_WT 0                          // 3 * 128 * 1024 f16 = 786432 B (swizzled tiles)
#define OFF_QS (786432)                   // 16384*128 f16 = 4 MiB
#define OFF_KS (786432 + 4194304)
#define OFF_VT (786432 + 2 * 4194304)     // vt[b][dv][key] transposed

// ---------------- weight prep --------------------------------------------
// wt layout: per matrix m, 16 k-tiles of 64 k; each tile = 1024 chunks of
// 16B (8 f16). Logical chunk (n, c): W[k0+c*8+j][n]*scale, j=0..7.
// Physical chunk p = n*8 + (c ^ (n&7))  -> conflict-free LDS reads in proj.
// grid (16, 3), block 256. Coalesced reads (tile is contiguous 32KB of W).
__global__ __launch_bounds__(256) void wprep_kernel(
    const float* __restrict__ Wq, const float* __restrict__ Wk,
    const float* __restrict__ Wv, _Float16* __restrict__ wt)
{
    __shared__ _Float16 T[64 * 136];   // [k][n] pad->136
    const int t = threadIdx.x;
    const int kt = blockIdx.x;
    const int m = blockIdx.y;
    const float* W = (m == 0) ? Wq : (m == 1) ? Wk : Wv;
    const float scale = (m == 0) ? INV_TEMP : 1.0f;
    const float* src = W + kt * 8192;   // 64 rows x 128 cols, contiguous

    #pragma unroll
    for (int i = 0; i < 8; i++) {
        int f = i * 1024 + t * 4;
        float4 v = *(const float4*)(src + f);
        int k = f >> 7, n = f & 127;
        _Float16* d = T + k * 136 + n;
        d[0] = (_Float16)(v.x * scale);
        d[1] = (_Float16)(v.y * scale);
        d[2] = (_Float16)(v.z * scale);
        d[3] = (_Float16)(v.w * scale);
    }
    __syncthreads();

    _Float16* dst = wt + m * 131072 + kt * 8192;
    #pragma unroll
    for (int i = 0; i < 4; i++) {
        int p = i * 256 + t;
        int n = p >> 3;
        int c = (p & 7) ^ (n & 7);
        half8 h;
        #pragma unroll
        for (int j = 0; j < 8; j++)
            h[j] = T[(c * 8 + j) * 136 + n];
        *(half8*)(dst + p * 8) = h;
    }
}

// ---------------- fused QKV projection -----------------------------------
// grid (256, 3); block 256 (4 waves). Tile: 64 rows x 128 cols, BK=64.
// A: direct global->reg, register double-buffered (no LDS, no conflicts).
// B: global_load_lds width=16 into double-buffered LDS, XOR-swizzled chunks.
// One barrier per K-step.
__global__ __launch_bounds__(256) void proj_kernel(
    const float* __restrict__ Xq, const float* __restrict__ Xk,
    const float* __restrict__ Xv, const _Float16* __restrict__ wt,
    _Float16* __restrict__ qs, _Float16* __restrict__ ks,
    _Float16* __restrict__ vt)
{
    __shared__ _Float16 Bs[2][8192];   // 2 x 16KB

    const int t = threadIdx.x;
    const int lane = t & 63;
    const int w = t >> 6;
    const int quad = lane >> 4;
    const int m16 = lane & 15;
    const int yb = blockIdx.y;
    const float* X = (yb == 0) ? Xq : (yb == 1) ? Xk : Xv;
    const _Float16* W = wt + yb * 131072;
    const int m0 = blockIdx.x * 64;
    const int row = m0 + w * 16 + m16;
    const float* arow = X + (size_t)row * 1024;

    floatx4 acc[8] = {};

    // B-fragment swizzled chunk offsets (constant across the K loop)
    const int sw0 = (quad) ^ (m16 & 7);
    const int sw1 = (4 + quad) ^ (m16 & 7);

    // ---- async B staging: tile kt -> Bs[buf] (16KB, contiguous source)
    auto stageB = [&](int buf, int kt) {
        const _Float16* src = W + kt * 8192;
        #pragma unroll
        for (int i = 0; i < 4; i++) {
            int slotbase = (w * 4 + i) * 64;
            __builtin_amdgcn_global_load_lds(
                (const __attribute__((address_space(1))) unsigned int*)(src + (size_t)(slotbase + lane) * 8),
                (__attribute__((address_space(3))) unsigned int*)(&Bs[buf][(slotbase + lane) * 8]),
                16, 0, 0);
        }
    };

    // prologue: tile 0
    stageB(0, 0);
    float4 a0 = *(const float4*)(arow + quad * 8);
    float4 a1 = *(const float4*)(arow + quad * 8 + 4);
    float4 a2 = *(const float4*)(arow + 32 + quad * 8);
    float4 a3 = *(const float4*)(arow + 32 + quad * 8 + 4);
    __builtin_amdgcn_s_waitcnt(0);
    __syncthreads();

    for (int kt = 0; kt < 16; kt++) {
        const int cur = kt & 1;
        float4 n0, n1, n2, n3;
        if (kt < 15) {
            stageB(cur ^ 1, kt + 1);
            const float* na = arow + (kt + 1) * 64;
            n0 = *(const float4*)(na + quad * 8);
            n1 = *(const float4*)(na + quad * 8 + 4);
            n2 = *(const float4*)(na + 32 + quad * 8);
            n3 = *(const float4*)(na + 32 + quad * 8 + 4);
        }

        half8 af0 = {(_Float16)a0.x, (_Float16)a0.y, (_Float16)a0.z, (_Float16)a0.w,
                     (_Float16)a1.x, (_Float16)a1.y, (_Float16)a1.z, (_Float16)a1.w};
        half8 af1 = {(_Float16)a2.x, (_Float16)a2.y, (_Float16)a2.z, (_Float16)a2.w,
                     (_Float16)a3.x, (_Float16)a3.y, (_Float16)a3.z, (_Float16)a3.w};

        const char* bb = (const char*)&Bs[cur][0];
        #pragma unroll
        for (int nt = 0; nt < 8; nt++) {
            half8 bf = *(const half8*)(bb + (nt * 16 + m16) * 128 + sw0 * 16);
            acc[nt] = __builtin_amdgcn_mfma_f32_16x16x32_f16(af0, bf, acc[nt], 0, 0, 0);
        }
        #pragma unroll
        for (int nt = 0; nt < 8; nt++) {
            half8 bf = *(const half8*)(bb + (nt * 16 + m16) * 128 + sw1 * 16);
            acc[nt] = __builtin_amdgcn_mfma_f32_16x16x32_f16(af1, bf, acc[nt], 0, 0, 0);
        }

        a0 = n0; a1 = n1; a2 = n2; a3 = n3;
        __builtin_amdgcn_s_waitcnt(0);   // drain async B(kt+1) + A prefetch
        __syncthreads();
    }

    if (yb < 2) {
        _Float16* out = (yb == 0) ? qs : ks;
        #pragma unroll
        for (int nt = 0; nt < 8; nt++) {
            #pragma unroll
            for (int r = 0; r < 4; r++) {
                int orow = m0 + w * 16 + quad * 4 + r;
                out[(size_t)orow * 128 + nt * 16 + m16] = (_Float16)acc[nt][r];
            }
        }
    } else {
        // transpose via LDS -> vt[b][dv][key]
        _Float16* T = &Bs[0][0];   // 64 x 130 = 16.6KB, fits in the 32KB
        #pragma unroll
        for (int nt = 0; nt < 8; nt++) {
            #pragma unroll
            for (int r = 0; r < 4; r++)
                T[(w * 16 + quad * 4 + r) * 130 + nt * 16 + m16] = (_Float16)acc[nt][r];
        }
        __syncthreads();
        int dv = t >> 1, hf = t & 1;
        int bb2 = m0 >> 11;
        int key0 = (m0 & 2047) + hf * 32;
        _Float16* dst = vt + (size_t)(bb2 * 128 + dv) * 2048 + key0;
        #pragma unroll
        for (int j8 = 0; j8 < 4; j8++) {
            half8 h;
            #pragma unroll
            for (int j = 0; j < 8; j++)
                h[j] = T[(hf * 32 + j8 * 8 + j) * 130 + dv];
            *(half8*)(dst + j8 * 8) = h;
        }
    }
}

// ---------------- flash attention (unchanged this round) -------------------
__global__ __launch_bounds__(256) void attn_kernel(
    const _Float16* __restrict__ qs, const _Float16* __restrict__ ks,
    const _Float16* __restrict__ vt, const int* __restrict__ mlen,
    float* __restrict__ out)
{
    __shared__ _Float16 kls[64 * 136];      // [key][136]
    __shared__ _Float16 vls[128 * 72];      // [dv][72]
    __shared__ _Float16 pls[4 * 16 * 72];   // per-wave [16][72]

    const int t = threadIdx.x;
    const int lane = t & 63;
    const int w = t >> 6;
    const int quad = lane >> 4;
    const int m16 = lane & 15;
    const int b = blockIdx.y;
    const int q0 = blockIdx.x * 64;
    const int ml = mlen[b];
    const int nkt = (ml + 63) >> 6;

    half8 aq[4];
    {
        const _Float16* qrow =
            qs + (size_t)(b * 2048 + q0 + w * 16 + m16) * 128 + quad * 8;
        #pragma unroll
        for (int d = 0; d < 4; d++)
            aq[d] = *(const half8*)(qrow + d * 32);
    }

    floatx4 acc[8] = {};
    float m_i[4] = {-3e38f, -3e38f, -3e38f, -3e38f};
    float l_i[4] = {0.f, 0.f, 0.f, 0.f};

    const int skey = t >> 2, sq4 = t & 3;
    const int sdv = t >> 1, shf = t & 1;

    for (int kt = 0; kt < nkt; kt++) {
        const int k0 = kt * 64;
        {
            const _Float16* src = ks + (size_t)(b * 2048 + k0 + skey) * 128 + sq4 * 32;
            _Float16* dst = kls + skey * 136 + sq4 * 32;
            #pragma unroll
            for (int i = 0; i < 4; i++)
                *(half8*)(dst + 8 * i) = ((const half8*)src)[i];
        }
        {
            const _Float16* src = vt + (size_t)(b * 128 + sdv) * 2048 + k0 + shf * 32;
            _Float16* dst = vls + sdv * 72 + shf * 32;
            #pragma unroll
            for (int i = 0; i < 4; i++)
                *(half8*)(dst + 8 * i) = ((const half8*)src)[i];
        }
        __syncthreads();

        floatx4 sacc[4] = {};
        #pragma unroll
        for (int d = 0; d < 4; d++) {
            #pragma unroll
            for (int nt = 0; nt < 4; nt++) {
                half8 bfrag = *(const half8*)(kls + (nt * 16 + m16) * 136 + d * 32 + quad * 8);
                sacc[nt] = __builtin_amdgcn_mfma_f32_16x16x32_f16(aq[d], bfrag, sacc[nt], 0, 0, 0);
            }
        }

        float p[4][4];
        float rowmax[4], rowsum[4];
        #pragma unroll
        for (int r = 0; r < 4; r++) rowmax[r] = -3e38f;
        #pragma unroll
        for (int nt = 0; nt < 4; nt++) {
            int key = k0 + nt * 16 + m16;
            bool valid = key < ml;
            #pragma unroll
            for (int r = 0; r < 4; r++) {
                float s = valid ? sacc[nt][r] : -3e38f;
                p[nt][r] = s;
                rowmax[r] = fmaxf(rowmax[r], s);
            }
        }
        #pragma unroll
        for (int mask = 8; mask >= 1; mask >>= 1) {
            #pragma unroll
            for (int r = 0; r < 4; r++)
                rowmax[r] = fmaxf(rowmax[r], __shfl_xor(rowmax[r], mask, 64));
        }
        #pragma unroll
        for (int r = 0; r < 4; r++) {
            float mnew = fmaxf(m_i[r], rowmax[r]);
            float alpha = __expf(m_i[r] - mnew);
            m_i[r] = mnew;
            l_i[r] *= alpha;
            #pragma unroll
            for (int nt = 0; nt < 8; nt++) acc[nt][r] *= alpha;
            rowsum[r] = 0.f;
            #pragma unroll
            for (int nt = 0; nt < 4; nt++) {
                float e = __expf(p[nt][r] - mnew);
                p[nt][r] = e;
                rowsum[r] += e;
            }
        }
        #pragma unroll
        for (int mask = 8; mask >= 1; mask >>= 1) {
            #pragma unroll
            for (int r = 0; r < 4; r++)
                rowsum[r] += __shfl_xor(rowsum[r], mask, 64);
        }
        #pragma unroll
        for (int r = 0; r < 4; r++) l_i[r] += rowsum[r];

        _Float16* pw = pls + w * 16 * 72;
        #pragma unroll
        for (int nt = 0; nt < 4; nt++) {
            #pragma unroll
            for (int r = 0; r < 4; r++)
                pw[(quad * 4 + r) * 72 + nt * 16 + m16] = (_Float16)p[nt][r];
        }
        __syncthreads();

        #pragma unroll
        for (int kp = 0; kp < 2; kp++) {
            half8 pa = *(const half8*)(pw + m16 * 72 + kp * 32 + quad * 8);
            #pragma unroll
            for (int nt = 0; nt < 8; nt++) {
                half8 bfrag = *(const half8*)(vls + (nt * 16 + m16) * 72 + kp * 32 + quad * 8);
                acc[nt] = __builtin_amdgcn_mfma_f32_16x16x32_f16(pa, bfrag, acc[nt], 0, 0, 0);
            }
        }
        __syncthreads();
    }

    #pragma unroll
    for (int r = 0; r < 4; r++) {
        float inv_l = 1.0f / l_i[r];
        int orow = b * 2048 + q0 + w * 16 + quad * 4 + r;
        float* dst = out + (size_t)orow * 128;
        #pragma unroll
        for (int nt = 0; nt < 8; nt++)
            dst[nt * 16 + m16] = acc[nt][r] * inv_l;
    }
}

extern "C" void kernel_launch(void* const* d_in, const int* in_sizes, int n_in,
                              void* d_out, int out_size, void* d_ws, size_t ws_size,
                              hipStream_t stream) {
    const float* q   = (const float*)d_in[0];
    const float* k   = (const float*)d_in[1];
    const float* v   = (const float*)d_in[2];
    const int* mlen  = (const int*)d_in[3];
    const float* Wq  = (const float*)d_in[4];
    const float* Wk  = (const float*)d_in[5];
    const float* Wv  = (const float*)d_in[6];
    float* out = (float*)d_out;

    char* ws = (char*)d_ws;
    _Float16* wt = (_Float16*)(ws + OFF_WT);
    _Float16* qs = (_Float16*)(ws + OFF_QS);
    _Float16* kss = (_Float16*)(ws + OFF_KS);
    _Float16* vt = (_Float16*)(ws + OFF_VT);

    hipLaunchKernelGGL(wprep_kernel, dim3(16, 3), dim3(256), 0, stream, Wq, Wk, Wv, wt);
    hipLaunchKernelGGL(proj_kernel, dim3(256, 3), dim3(256), 0, stream,
                       q, k, v, wt, qs, kss, vt);
    hipLaunchKernelGGL(attn_kernel, dim3(32, 8), dim3(256), 0, stream,
                       qs, kss, vt, mlen, out);
}

// Round 3
// 259.671 us; speedup vs baseline: 1.1131x; 1.1131x over previous
//
#include <hip/hip_runtime.h>

typedef _Float16 half8 __attribute__((ext_vector_type(8)));
typedef float floatx4 __attribute__((ext_vector_type(4)));

#define INV_TEMP 0.08838834764831845f

// ---------------- workspace layout (bytes) --------------------------------
#define OFF_WT   0                        // 3*128*1024 f16 = 786432 (swizzled)
#define OFF_QS   786432                   // qs linear [16384][128] f16, 4 MiB
#define OFF_KT   (786432 + 4194304)       // ks tiled:  [b][kt][1024 chunks]
#define OFF_VT   (OFF_KT + 4194304)       // vt tiled:  [b][kt][1024 chunks]
#define OFF_PART (OFF_VT + 4194304)       // partials: 2*8*2048*132 fp32
#define PART_BYTES (2ull * 8 * 2048 * 132 * 4)

// ---------------- weight prep (unchanged) ---------------------------------
// wt: per matrix m, 16 k-tiles of 64k; tile = 1024 chunks of 16B.
// physical chunk p = n*8 + (c ^ (n&7)), logical (n∈[0,128), c∈[0,8)).
__global__ __launch_bounds__(256) void wprep_kernel(
    const float* __restrict__ Wq, const float* __restrict__ Wk,
    const float* __restrict__ Wv, _Float16* __restrict__ wt)
{
    __shared__ _Float16 T[64 * 136];
    const int t = threadIdx.x;
    const int kt = blockIdx.x;
    const int m = blockIdx.y;
    const float* W = (m == 0) ? Wq : (m == 1) ? Wk : Wv;
    const float scale = (m == 0) ? INV_TEMP : 1.0f;
    const float* src = W + kt * 8192;

    #pragma unroll
    for (int i = 0; i < 8; i++) {
        int f = i * 1024 + t * 4;
        float4 v = *(const float4*)(src + f);
        int k = f >> 7, n = f & 127;
        _Float16* d = T + k * 136 + n;
        d[0] = (_Float16)(v.x * scale);
        d[1] = (_Float16)(v.y * scale);
        d[2] = (_Float16)(v.z * scale);
        d[3] = (_Float16)(v.w * scale);
    }
    __syncthreads();

    _Float16* dst = wt + m * 131072 + kt * 8192;
    #pragma unroll
    for (int i = 0; i < 4; i++) {
        int p = i * 256 + t;
        int n = p >> 3;
        int c = (p & 7) ^ (n & 7);
        half8 h;
        #pragma unroll
        for (int j = 0; j < 8; j++)
            h[j] = T[(c * 8 + j) * 136 + n];
        *(half8*)(dst + p * 8) = h;
    }
}

// ---------------- fused QKV projection ------------------------------------
// grid (256,3); block 256 (4 waves). 64 rows x 128 cols, BK=128 supersteps.
// A: global_load_lds fp32, 2 contiguous rows per instruction (<=3 pages),
//    global-side XOR chunk swizzle -> balanced LDS fragment reads.
// B: global_load_lds from swizzled wt (contiguous 16KB/tile).
__global__ __launch_bounds__(256) void proj_kernel(
    const float* __restrict__ Xq, const float* __restrict__ Xk,
    const float* __restrict__ Xv, const _Float16* __restrict__ wt,
    _Float16* __restrict__ qs, _Float16* __restrict__ ks_t,
    _Float16* __restrict__ vt_t)
{
    __shared__ float As[64 * 128];        // 32 KB fp32, swizzled chunks/row
    __shared__ _Float16 Bs[2 * 8192];     // 32 KB: two 64-k tiles

    const int t = threadIdx.x;
    const int lane = t & 63;
    const int w = t >> 6;
    const int quad = lane >> 4;
    const int m16 = lane & 15;
    const int yb = blockIdx.y;
    const float* X = (yb == 0) ? Xq : (yb == 1) ? Xk : Xv;
    const _Float16* W = wt + yb * 131072;
    const int m0 = blockIdx.x * 64;

    floatx4 acc[8] = {};
    const int e = m16 & 7;

    for (int s = 0; s < 8; s++) {
        if (s) __syncthreads();
        {   // stage A: 64 rows x 128 floats (2048 16B chunks)
            const float* base = X + (size_t)m0 * 1024 + s * 128;
            #pragma unroll
            for (int i = 0; i < 8; i++) {
                int st = i * 256 + t;
                int row = st >> 5;
                int p = st & 31;
                int c = (p & 24) | ((p & 7) ^ (row & 7));
                __builtin_amdgcn_global_load_lds(
                    (const __attribute__((address_space(1))) unsigned int*)(base + (size_t)row * 1024 + c * 4),
                    (__attribute__((address_space(3))) unsigned int*)(As + st * 4),
                    16, 0, 0);
            }
        }
        {   // stage B: two 64-k tiles = 2048 16B chunks, contiguous source
            const _Float16* src = W + s * 16384;
            #pragma unroll
            for (int i = 0; i < 8; i++) {
                int slot = (w * 8 + i) * 64 + lane;
                __builtin_amdgcn_global_load_lds(
                    (const __attribute__((address_space(1))) unsigned int*)(src + (size_t)slot * 8),
                    (__attribute__((address_space(3))) unsigned int*)(Bs + slot * 8),
                    16, 0, 0);
            }
        }
        __builtin_amdgcn_s_waitcnt(0);
        __syncthreads();

        const float* ap = As + (w * 16 + m16) * 128;
        #pragma unroll
        for (int ks = 0; ks < 2; ks++) {
            const char* bt = (const char*)(Bs + ks * 8192);
            #pragma unroll
            for (int hf2 = 0; hf2 < 2; hf2++) {
                int b16 = ks * 16 + hf2 * 8;
                float4 fa = *(const float4*)(ap + (b16 + ((quad * 2) ^ e)) * 4);
                float4 fb = *(const float4*)(ap + (b16 + ((quad * 2 + 1) ^ e)) * 4);
                half8 af = {(_Float16)fa.x, (_Float16)fa.y, (_Float16)fa.z, (_Float16)fa.w,
                            (_Float16)fb.x, (_Float16)fb.y, (_Float16)fb.z, (_Float16)fb.w};
                int sw = (hf2 * 4 + quad) ^ e;
                #pragma unroll
                for (int nt = 0; nt < 8; nt++) {
                    half8 bf = *(const half8*)(bt + (nt * 16 + m16) * 128 + sw * 16);
                    acc[nt] = __builtin_amdgcn_mfma_f32_16x16x32_f16(af, bf, acc[nt], 0, 0, 0);
                }
            }
        }
    }

    const int b = m0 >> 11;
    const int kt = (m0 & 2047) >> 6;

    if (yb == 0) {
        #pragma unroll
        for (int nt = 0; nt < 8; nt++) {
            #pragma unroll
            for (int r = 0; r < 4; r++) {
                int orow = m0 + w * 16 + quad * 4 + r;
                qs[(size_t)orow * 128 + nt * 16 + m16] = (_Float16)acc[nt][r];
            }
        }
    } else if (yb == 1) {
        // ks tiled: chunk p = row*16 + (d8 ^ (row&7))
        _Float16* tile = ks_t + (size_t)(b * 32 + kt) * 8192;
        #pragma unroll
        for (int nt = 0; nt < 8; nt++) {
            #pragma unroll
            for (int r = 0; r < 4; r++) {
                int row = w * 16 + quad * 4 + r;
                int col = nt * 16 + m16;
                int p = row * 16 + ((col >> 3) ^ (row & 7));
                tile[p * 8 + (col & 7)] = (_Float16)acc[nt][r];
            }
        }
    } else {
        // vt tiled: transpose via LDS, chunk p = dv*8 + (k8 ^ (dv&7))
        __syncthreads();
        _Float16* T = (_Float16*)As;   // 64 x 130 f16
        #pragma unroll
        for (int nt = 0; nt < 8; nt++) {
            #pragma unroll
            for (int r = 0; r < 4; r++)
                T[(w * 16 + quad * 4 + r) * 130 + nt * 16 + m16] = (_Float16)acc[nt][r];
        }
        __syncthreads();
        int dv = t >> 1, hf = t & 1;
        _Float16* tile = vt_t + (size_t)(b * 32 + kt) * 8192;
        #pragma unroll
        for (int j8 = 0; j8 < 4; j8++) {
            int k8 = hf * 4 + j8;
            half8 h;
            #pragma unroll
            for (int j = 0; j < 8; j++)
                h[j] = T[(k8 * 8 + j) * 130 + dv];
            int p = dv * 8 + (k8 ^ (dv & 7));
            *(half8*)(tile + p * 8) = h;
        }
    }
}

// ---------------- flash attention -----------------------------------------
// grid (32, 8, ns); block 256. Double-buffered async K/V tiles, one barrier
// per key tile. ns==2: key-split halves write unnormalized partials + (m,l).
__global__ __launch_bounds__(256) void attn_kernel(
    const _Float16* __restrict__ qs, const _Float16* __restrict__ ks_t,
    const _Float16* __restrict__ vt_t, const int* __restrict__ mlen,
    float* __restrict__ out, float* __restrict__ part, int ns)
{
    __shared__ _Float16 kbuf[2 * 8192];     // 32 KB
    __shared__ _Float16 vbuf[2 * 8192];     // 32 KB
    __shared__ _Float16 pls[4 * 16 * 72];   // per-wave P

    const int t = threadIdx.x;
    const int lane = t & 63;
    const int w = t >> 6;
    const int quad = lane >> 4;
    const int m16 = lane & 15;
    const int b = blockIdx.y;
    const int h = blockIdx.z;
    const int q0 = blockIdx.x * 64;
    const int ml = mlen[b];
    const int nkt = (ml + 63) >> 6;
    const int hs = (nkt + ns - 1) / ns;
    const int kb0 = h * hs;
    const int kb1 = min(nkt, (h + 1) * hs);

    half8 aq[4];
    {
        const _Float16* qrow =
            qs + (size_t)(b * 2048 + q0 + w * 16 + m16) * 128 + quad * 8;
        #pragma unroll
        for (int d = 0; d < 4; d++)
            aq[d] = *(const half8*)(qrow + d * 32);
    }

    floatx4 acc[8] = {};
    float m_i[4] = {-3e38f, -3e38f, -3e38f, -3e38f};
    float l_i[4] = {0.f, 0.f, 0.f, 0.f};

    auto stage = [&](int buf, int kt) {
        const _Float16* ksrc = ks_t + (size_t)(b * 32 + kt) * 8192;
        const _Float16* vsrc = vt_t + (size_t)(b * 32 + kt) * 8192;
        #pragma unroll
        for (int i = 0; i < 4; i++) {
            int slot = (w * 4 + i) * 64 + lane;
            __builtin_amdgcn_global_load_lds(
                (const __attribute__((address_space(1))) unsigned int*)(ksrc + (size_t)slot * 8),
                (__attribute__((address_space(3))) unsigned int*)(kbuf + buf * 8192 + slot * 8),
                16, 0, 0);
            __builtin_amdgcn_global_load_lds(
                (const __attribute__((address_space(1))) unsigned int*)(vsrc + (size_t)slot * 8),
                (__attribute__((address_space(3))) unsigned int*)(vbuf + buf * 8192 + slot * 8),
                16, 0, 0);
        }
    };

    if (kb0 < kb1) {
        stage(0, kb0);
        __builtin_amdgcn_s_waitcnt(0);
        __syncthreads();

        for (int kt = kb0; kt < kb1; kt++) {
            const int cur = (kt - kb0) & 1;
            if (kt + 1 < kb1) stage(cur ^ 1, kt + 1);

            const _Float16* kb = kbuf + cur * 8192;
            const _Float16* vb = vbuf + cur * 8192;
            const int k0 = kt * 64;

            // S = (Q/temp) K^T
            floatx4 sacc[4] = {};
            #pragma unroll
            for (int d = 0; d < 4; d++) {
                #pragma unroll
                for (int nt = 0; nt < 4; nt++) {
                    int row = nt * 16 + m16;
                    int p = row * 16 + ((d * 4 + quad) ^ (row & 7));
                    half8 bf = *(const half8*)(kb + p * 8);
                    sacc[nt] = __builtin_amdgcn_mfma_f32_16x16x32_f16(aq[d], bf, sacc[nt], 0, 0, 0);
                }
            }

            // online softmax
            float p4[4][4];
            float rowmax[4], rowsum[4];
            #pragma unroll
            for (int r = 0; r < 4; r++) rowmax[r] = -3e38f;
            #pragma unroll
            for (int nt = 0; nt < 4; nt++) {
                int key = k0 + nt * 16 + m16;
                bool valid = key < ml;
                #pragma unroll
                for (int r = 0; r < 4; r++) {
                    float s = valid ? sacc[nt][r] : -3e38f;
                    p4[nt][r] = s;
                    rowmax[r] = fmaxf(rowmax[r], s);
                }
            }
            #pragma unroll
            for (int mask = 8; mask >= 1; mask >>= 1) {
                #pragma unroll
                for (int r = 0; r < 4; r++)
                    rowmax[r] = fmaxf(rowmax[r], __shfl_xor(rowmax[r], mask, 64));
            }
            #pragma unroll
            for (int r = 0; r < 4; r++) {
                float mnew = fmaxf(m_i[r], rowmax[r]);
                float alpha = __expf(m_i[r] - mnew);
                m_i[r] = mnew;
                l_i[r] *= alpha;
                #pragma unroll
                for (int nt = 0; nt < 8; nt++) acc[nt][r] *= alpha;
                rowsum[r] = 0.f;
                #pragma unroll
                for (int nt = 0; nt < 4; nt++) {
                    float ee = __expf(p4[nt][r] - mnew);
                    p4[nt][r] = ee;
                    rowsum[r] += ee;
                }
            }
            #pragma unroll
            for (int mask = 8; mask >= 1; mask >>= 1) {
                #pragma unroll
                for (int r = 0; r < 4; r++)
                    rowsum[r] += __shfl_xor(rowsum[r], mask, 64);
            }
            #pragma unroll
            for (int r = 0; r < 4; r++) l_i[r] += rowsum[r];

            // P: C-layout -> A-layout, per-wave LDS (no barrier needed)
            _Float16* pw = pls + w * 16 * 72;
            #pragma unroll
            for (int nt = 0; nt < 4; nt++) {
                #pragma unroll
                for (int r = 0; r < 4; r++)
                    pw[(quad * 4 + r) * 72 + nt * 16 + m16] = (_Float16)p4[nt][r];
            }

            // O += P @ V
            #pragma unroll
            for (int kp = 0; kp < 2; kp++) {
                half8 pa = *(const half8*)(pw + m16 * 72 + kp * 32 + quad * 8);
                #pragma unroll
                for (int nt = 0; nt < 8; nt++) {
                    int dv = nt * 16 + m16;
                    int p = dv * 8 + ((kp * 4 + quad) ^ (dv & 7));
                    half8 bf = *(const half8*)(vb + p * 8);
                    acc[nt] = __builtin_amdgcn_mfma_f32_16x16x32_f16(pa, bf, acc[nt], 0, 0, 0);
                }
            }

            __builtin_amdgcn_s_waitcnt(0);
            __syncthreads();
        }
    }

    if (ns == 1) {
        #pragma unroll
        for (int r = 0; r < 4; r++) {
            float inv_l = 1.0f / l_i[r];
            int orow = b * 2048 + q0 + w * 16 + quad * 4 + r;
            float* dst = out + (size_t)orow * 128;
            #pragma unroll
            for (int nt = 0; nt < 8; nt++)
                dst[nt * 16 + m16] = acc[nt][r] * inv_l;
        }
    } else {
        #pragma unroll
        for (int r = 0; r < 4; r++) {
            float* pr = part +
                (size_t)(h * 16384 + b * 2048 + q0 + w * 16 + quad * 4 + r) * 132;
            #pragma unroll
            for (int nt = 0; nt < 8; nt++)
                pr[nt * 16 + m16] = acc[nt][r];
            if (m16 == 0) { pr[128] = m_i[r]; pr[129] = l_i[r]; }
        }
    }
}

// ---------------- merge (ns==2 only) ---------------------------------------
__global__ __launch_bounds__(256) void merge_kernel(
    const float* __restrict__ part, float* __restrict__ out)
{
    int idx = blockIdx.x * 256 + threadIdx.x;   // 2,097,152 elements
    int row = idx >> 7, c = idx & 127;
    const float* p1 = part + (size_t)row * 132;
    const float* p2 = part + (size_t)(16384 + row) * 132;
    float m1 = p1[128], l1 = p1[129];
    float m2 = p2[128], l2 = p2[129];
    float M = fmaxf(m1, m2);
    float s1 = __expf(m1 - M), s2 = __expf(m2 - M);
    out[idx] = (p1[c] * s1 + p2[c] * s2) / (l1 * s1 + l2 * s2);
}

extern "C" void kernel_launch(void* const* d_in, const int* in_sizes, int n_in,
                              void* d_out, int out_size, void* d_ws, size_t ws_size,
                              hipStream_t stream) {
    const float* q   = (const float*)d_in[0];
    const float* k   = (const float*)d_in[1];
    const float* v   = (const float*)d_in[2];
    const int* mlen  = (const int*)d_in[3];
    const float* Wq  = (const float*)d_in[4];
    const float* Wk  = (const float*)d_in[5];
    const float* Wv  = (const float*)d_in[6];
    float* out = (float*)d_out;

    char* ws = (char*)d_ws;
    _Float16* wt   = (_Float16*)(ws + OFF_WT);
    _Float16* qs   = (_Float16*)(ws + OFF_QS);
    _Float16* ks_t = (_Float16*)(ws + OFF_KT);
    _Float16* vt_t = (_Float16*)(ws + OFF_VT);
    float* part    = (float*)(ws + OFF_PART);

    const int ns = (ws_size >= (size_t)OFF_PART + PART_BYTES) ? 2 : 1;

    hipLaunchKernelGGL(wprep_kernel, dim3(16, 3), dim3(256), 0, stream, Wq, Wk, Wv, wt);
    hipLaunchKernelGGL(proj_kernel, dim3(256, 3), dim3(256), 0, stream,
                       q, k, v, wt, qs, ks_t, vt_t);
    hipLaunchKernelGGL(attn_kernel, dim3(32, 8, ns), dim3(256), 0, stream,
                       qs, ks_t, vt_t, mlen, out, part, ns);
    if (ns == 2)
        hipLaunchKernelGGL(merge_kernel, dim3(8192), dim3(256), 0, stream, part, out);
}